// Round 7
// baseline (91.887 us; speedup 1.0000x reference)
//
#include <hip/hip_runtime.h>

#define Hc     512
#define Wc     512
#define OH     506
#define OW     506
#define NPIX   (Hc * Wc)
#define BATCH  64
#define CHUNKS 16

#define BH     16                          // output rows per band
#define NBAND  32                          // 32*16 = 512 >= 506
#define NW     3                           // waves per image-row span
#define WPB    4                           // waves per block
#define NPART  (BATCH * NBAND * NW)        // 6144

typedef float f32x2 __attribute__((ext_vector_type(2)));
typedef float f32x4 __attribute__((ext_vector_type(4)));

// ---------------- Kernel 1: per-(sample,chunk) min/max partials -------------
__global__ __launch_bounds__(256) void mm_part_kernel(
    const float* __restrict__ X, const float* __restrict__ Y,
    float* __restrict__ part)
{
    int blk = blockIdx.x;            // 0 .. BATCH*CHUNKS-1
    int b   = blk >> 4;
    int ch  = blk & 15;
    size_t base = (size_t)b * NPIX + (size_t)ch * (NPIX / CHUNKS);
    const float4* x4 = (const float4*)(X + base);
    const float4* y4 = (const float4*)(Y + base);
    const int n4 = (NPIX / CHUNKS) / 4;   // 4096

    float mn = 1e38f, mx = -1e38f;
    for (int i = threadIdx.x; i < n4; i += 256) {
        float4 a = x4[i];
        float4 c = y4[i];
        mn = fminf(mn, fminf(fminf(a.x, a.y), fminf(a.z, a.w)));
        mx = fmaxf(mx, fmaxf(fmaxf(a.x, a.y), fmaxf(a.z, a.w)));
        mn = fminf(mn, fminf(fminf(c.x, c.y), fminf(c.z, c.w)));
        mx = fmaxf(mx, fmaxf(fmaxf(c.x, c.y), fmaxf(c.z, c.w)));
    }
    #pragma unroll
    for (int off = 1; off < 64; off <<= 1) {
        mn = fminf(mn, __shfl_xor(mn, off, 64));
        mx = fmaxf(mx, __shfl_xor(mx, off, 64));
    }
    __shared__ float smn[4], smx[4];
    int lane = threadIdx.x & 63, wid = threadIdx.x >> 6;
    if (lane == 0) { smn[wid] = mn; smx[wid] = mx; }
    __syncthreads();
    if (threadIdx.x == 0) {
        mn = fminf(fminf(smn[0], smn[1]), fminf(smn[2], smn[3]));
        mx = fmaxf(fmaxf(smx[0], smx[1]), fmaxf(smx[2], smx[3]));
        part[2 * blk]     = mn;
        part[2 * blk + 1] = mx;
    }
}

// ---------------- Kernel 2: pipelined 4-col/lane streaming SSIM -------------
// Each wave: 4 consecutive cols/lane (float4), covers 256 cols; 3 waves span
// a row (bases 0/248/496). Vertical 7-window = packed running sums + re-load
// of the outgoing row (L2-hot). Horizontal 7-window = 6 independent shuffles
// per stat + in-register slide. Distance-1 software pipeline (A/B reg sets).
// No LDS, no barriers.
__global__ __launch_bounds__(256, 6) void ssim_stream_kernel(
    const float* __restrict__ X, const float* __restrict__ Y,
    const float* __restrict__ mmpart, float* __restrict__ part)
{
    const int lane  = threadIdx.x & 63;
    const int wid   = threadIdx.x >> 6;
    const int chunk = blockIdx.x;               // 0..2
    const int band  = blockIdx.y * WPB + wid;   // 0..31
    const int img   = blockIdx.z;               // 0..63

    // fold chunk min/max -> C1, C2 (uniform; hidden under prologue loads)
    float mn = 1e38f, mx = -1e38f;
    #pragma unroll
    for (int ch = 0; ch < CHUNKS; ++ch) {
        mn = fminf(mn, mmpart[2 * (img * CHUNKS + ch)]);
        mx = fmaxf(mx, mmpart[2 * (img * CHUNKS + ch) + 1]);
    }
    const float dr = mx - mn;
    const float C1 = (0.01f * dr) * (0.01f * dr);
    const float C2 = (0.03f * dr) * (0.03f * dr);
    const f32x2 C1v = {C1, C1};
    const f32x2 C2v = {C2, C2};
    const f32x2 inv2  = {1.0f / 49.0f, 1.0f / 49.0f};
    const f32x2 covn2 = {49.0f / 48.0f, 49.0f / 48.0f};

    // chunk geometry
    const int cbase  = (chunk == 0) ? 0 : (chunk == 1) ? 248 : 496;
    const int out_lo = (chunk == 0) ? 0 : (chunk == 1) ? 250 : 498;
    const int out_hi = (chunk == 0) ? 249 : (chunk == 1) ? 497 : 505;

    const int col0  = cbase + 4 * lane;             // logical first col
    const int col0c = (col0 < 508) ? col0 : 508;    // clamped, 16B aligned
    f32x2 vm01, vm23;
    {
        float v[4];
        #pragma unroll
        for (int j = 0; j < 4; ++j) {
            int oc = col0 + j;
            v[j] = (oc >= out_lo && oc <= out_hi) ? 1.0f : 0.0f;
        }
        vm01 = (f32x2){v[0], v[1]};
        vm23 = (f32x2){v[2], v[3]};
    }

    const int oy0 = band * BH;
    const int nvalid = (OH - oy0) < BH ? (OH - oy0) : BH;   // 16 or 10 (even)

    const float* px = X + (size_t)img * NPIX + col0c;
    const float* py = Y + (size_t)img * NPIX + col0c;

    // packed running vertical sums for own 4 columns: [0]=cols 0,1 [1]=cols 2,3
    f32x2 Vx[2]  = {{0,0},{0,0}}, Vy[2]  = {{0,0},{0,0}};
    f32x2 Vxy[2] = {{0,0},{0,0}}, Vss[2] = {{0,0},{0,0}};

    #define VADD(xa, ya)                                                     \
    {                                                                        \
        f32x2 xl = (xa).lo, xh = (xa).hi, yl = (ya).lo, yh = (ya).hi;        \
        Vx[0] += xl; Vx[1] += xh; Vy[0] += yl; Vy[1] += yh;                  \
        Vxy[0] += xl * yl; Vxy[1] += xh * yh;                                \
        Vss[0] += xl * xl + yl * yl; Vss[1] += xh * xh + yh * yh;            \
    }
    #define VSUB(xa, ya)                                                     \
    {                                                                        \
        f32x2 xl = (xa).lo, xh = (xa).hi, yl = (ya).lo, yh = (ya).hi;        \
        Vx[0] -= xl; Vx[1] -= xh; Vy[0] -= yl; Vy[1] -= yh;                  \
        Vxy[0] -= xl * yl; Vxy[1] -= xh * yh;                                \
        Vss[0] -= xl * xl + yl * yl; Vss[1] -= xh * xh + yh * yh;            \
    }

    // prologue: accumulate rows oy0..oy0+5
    #pragma unroll
    for (int k = 0; k < 6; ++k) {
        f32x4 xa = *(const f32x4*)(px + (size_t)(oy0 + k) * Wc);
        f32x4 ya = *(const f32x4*)(py + (size_t)(oy0 + k) * Wc);
        VADD(xa, ya)
    }

    f32x2 acc2 = {0.f, 0.f};

    // horizontal 7-window: 6 independent shuffles per stat + slide
    #define H7(V, S0, S1, S2, S3)                                            \
    {                                                                        \
        float v0 = V[0].x, v1 = V[0].y, v2 = V[1].x, v3 = V[1].y;            \
        float n0 = __shfl_down(v0, 1, 64);                                   \
        float n1 = __shfl_down(v1, 1, 64);                                   \
        float n2 = __shfl_down(v2, 1, 64);                                   \
        float n3 = __shfl_down(v3, 1, 64);                                   \
        float m0 = __shfl_down(v0, 2, 64);                                   \
        float m1 = __shfl_down(v1, 2, 64);                                   \
        S0 = ((v0 + v1) + (v2 + v3)) + ((n0 + n1) + n2);                     \
        S1 = S0 + n3 - v0;                                                   \
        S2 = S1 + m0 - v1;                                                   \
        S3 = S2 + m1 - v2;                                                   \
    }

    // packed SSIM for a float2 window pair
    #define SSIM2(wx, wy, wp, ws, vmv)                                       \
    {                                                                        \
        f32x2 ux   = wx * inv2;                                              \
        f32x2 uy   = wy * inv2;                                              \
        f32x2 uxuy = ux * uy;                                                \
        f32x2 u2   = ux * ux + uy * uy;                                      \
        f32x2 vxy  = (wp * inv2 - uxuy) * covn2;                             \
        f32x2 vss  = (ws * inv2 - u2) * covn2;                               \
        f32x2 A1   = uxuy + uxuy + C1v;                                      \
        f32x2 A2   = vxy + vxy + C2v;                                        \
        f32x2 B1   = u2 + C1v;                                               \
        f32x2 B2   = vss + C2v;                                              \
        f32x2 den  = B1 * B2;                                                \
        f32x2 num  = A1 * A2;                                                \
        f32x2 rv   = {__builtin_amdgcn_rcpf(den.x),                          \
                      __builtin_amdgcn_rcpf(den.y)};                         \
        acc2 += num * rv * vmv;                                              \
    }

    #define BODY(xin, yin, xout, yout)                                       \
    {                                                                        \
        VADD(xin, yin)                                                       \
        float Wx0, Wx1, Wx2, Wx3;  H7(Vx,  Wx0, Wx1, Wx2, Wx3)              \
        float Wy0, Wy1, Wy2, Wy3;  H7(Vy,  Wy0, Wy1, Wy2, Wy3)              \
        float Wp0, Wp1, Wp2, Wp3;  H7(Vxy, Wp0, Wp1, Wp2, Wp3)              \
        float Ws0, Ws1, Ws2, Ws3;  H7(Vss, Ws0, Ws1, Ws2, Ws3)              \
        f32x2 wx01 = {Wx0, Wx1}, wx23 = {Wx2, Wx3};                          \
        f32x2 wy01 = {Wy0, Wy1}, wy23 = {Wy2, Wy3};                          \
        f32x2 wp01 = {Wp0, Wp1}, wp23 = {Wp2, Wp3};                          \
        f32x2 ws01 = {Ws0, Ws1}, ws23 = {Ws2, Ws3};                          \
        SSIM2(wx01, wy01, wp01, ws01, vm01)                                  \
        SSIM2(wx23, wy23, wp23, ws23, vm23)                                  \
        VSUB(xout, yout)                                                     \
    }

    // distance-1 software pipeline, hand-rotated A/B register sets.
    // iter tt uses: incoming row oy0+tt+6, outgoing row oy0+tt.
    const size_t W = Wc;
    f32x4 xiA = *(const f32x4*)(px + (size_t)(oy0 + 6) * W);
    f32x4 yiA = *(const f32x4*)(py + (size_t)(oy0 + 6) * W);
    f32x4 xoA = *(const f32x4*)(px + (size_t)oy0 * W);
    f32x4 yoA = *(const f32x4*)(py + (size_t)oy0 * W);

    for (int tt = 0; tt < nvalid; tt += 2) {
        // prefetch iter tt+1 (in-row clamp to 511; harmless over-read)
        int ri1 = oy0 + tt + 7; if (ri1 > 511) ri1 = 511;
        f32x4 xiB = *(const f32x4*)(px + (size_t)ri1 * W);
        f32x4 yiB = *(const f32x4*)(py + (size_t)ri1 * W);
        f32x4 xoB = *(const f32x4*)(px + (size_t)(oy0 + tt + 1) * W);
        f32x4 yoB = *(const f32x4*)(py + (size_t)(oy0 + tt + 1) * W);

        BODY(xiA, yiA, xoA, yoA)

        // prefetch iter tt+2
        int ri2 = oy0 + tt + 8; if (ri2 > 511) ri2 = 511;
        xiA = *(const f32x4*)(px + (size_t)ri2 * W);
        yiA = *(const f32x4*)(py + (size_t)ri2 * W);
        xoA = *(const f32x4*)(px + (size_t)(oy0 + tt + 2) * W);
        yoA = *(const f32x4*)(py + (size_t)(oy0 + tt + 2) * W);

        BODY(xiB, yiB, xoB, yoB)
    }

    #undef BODY
    #undef SSIM2
    #undef H7
    #undef VADD
    #undef VSUB

    float acc = acc2.x + acc2.y;
    // deterministic wave reduce
    #pragma unroll
    for (int off = 1; off < 64; off <<= 1)
        acc += __shfl_xor(acc, off, 64);
    if (lane == 0)
        part[((size_t)img * NBAND + band) * NW + chunk] = acc;
}

// ---------------- Kernel 3: final deterministic f64 reduction ---------------
__global__ __launch_bounds__(1024) void final_reduce_kernel(
    const float* __restrict__ part, float* __restrict__ out)
{
    __shared__ double sd[1024];
    double s = 0.0;
    for (int i = threadIdx.x; i < NPART; i += 1024)
        s += (double)part[i];
    sd[threadIdx.x] = s;
    __syncthreads();
    for (int off = 512; off > 0; off >>= 1) {
        if (threadIdx.x < off) sd[threadIdx.x] += sd[threadIdx.x + off];
        __syncthreads();
    }
    if (threadIdx.x == 0)
        out[0] = (float)(sd[0] / ((double)BATCH * OH * OW));
}

extern "C" void kernel_launch(void* const* d_in, const int* in_sizes, int n_in,
                              void* d_out, int out_size, void* d_ws, size_t ws_size,
                              hipStream_t stream) {
    const float* X = (const float*)d_in[0];
    const float* Y = (const float*)d_in[1];
    float* out = (float*)d_out;
    float* ws  = (float*)d_ws;

    float* mmpart = ws;                 // 2 * BATCH * CHUNKS = 2048 floats
    float* part   = ws + 2048;          // NPART = 6144 floats

    mm_part_kernel<<<BATCH * CHUNKS, 256, 0, stream>>>(X, Y, mmpart);
    dim3 grid(NW, NBAND / WPB, BATCH);
    ssim_stream_kernel<<<grid, 64 * WPB, 0, stream>>>(X, Y, mmpart, part);
    final_reduce_kernel<<<1, 1024, 0, stream>>>(part, out);
}

// Round 8
// 84.454 us; speedup vs baseline: 1.0880x; 1.0880x over previous
//
#include <hip/hip_runtime.h>

#define Hc     512
#define Wc     512
#define OH     506
#define OW     506
#define NPIX   (Hc * Wc)
#define BATCH  64
#define CHUNKS 16

#define BH     14                          // output rows per band (2 groups of 7)
#define NBAND  37                          // 36*14=504, band 36 covers rows 504-505
#define NW     3                           // waves per image-row span
#define WPB    4                           // waves per block
#define GYD    ((NBAND + WPB - 1) / WPB)   // 10
#define NPART  (BATCH * NBAND * NW)        // 7104

typedef float f32x2 __attribute__((ext_vector_type(2)));
typedef float f32x4 __attribute__((ext_vector_type(4)));

// ---------------- Kernel 1: per-(sample,chunk) min/max partials -------------
__global__ __launch_bounds__(256) void mm_part_kernel(
    const float* __restrict__ X, const float* __restrict__ Y,
    float* __restrict__ part)
{
    int blk = blockIdx.x;            // 0 .. BATCH*CHUNKS-1
    int b   = blk >> 4;
    int ch  = blk & 15;
    size_t base = (size_t)b * NPIX + (size_t)ch * (NPIX / CHUNKS);
    const float4* x4 = (const float4*)(X + base);
    const float4* y4 = (const float4*)(Y + base);
    const int n4 = (NPIX / CHUNKS) / 4;   // 4096

    float mn = 1e38f, mx = -1e38f;
    for (int i = threadIdx.x; i < n4; i += 256) {
        float4 a = x4[i];
        float4 c = y4[i];
        mn = fminf(mn, fminf(fminf(a.x, a.y), fminf(a.z, a.w)));
        mx = fmaxf(mx, fmaxf(fmaxf(a.x, a.y), fmaxf(a.z, a.w)));
        mn = fminf(mn, fminf(fminf(c.x, c.y), fminf(c.z, c.w)));
        mx = fmaxf(mx, fmaxf(fmaxf(c.x, c.y), fmaxf(c.z, c.w)));
    }
    #pragma unroll
    for (int off = 1; off < 64; off <<= 1) {
        mn = fminf(mn, __shfl_xor(mn, off, 64));
        mx = fmaxf(mx, __shfl_xor(mx, off, 64));
    }
    __shared__ float smn[4], smx[4];
    int lane = threadIdx.x & 63, wid = threadIdx.x >> 6;
    if (lane == 0) { smn[wid] = mn; smx[wid] = mx; }
    __syncthreads();
    if (threadIdx.x == 0) {
        mn = fminf(fminf(smn[0], smn[1]), fminf(smn[2], smn[3]));
        mx = fmaxf(fmaxf(smx[0], smx[1]), fmaxf(smx[2], smx[3]));
        part[2 * blk]     = mn;
        part[2 * blk + 1] = mx;
    }
}

// ---------------- Kernel 2: group-prefetched streaming SSIM -----------------
// Each wave: 4 consecutive cols/lane (f32x4), covers 256 cols; 3 waves span a
// row (bases 0/248/496). Band of 14 output rows = 2 groups of 7: all 14
// incoming-row loads issued at group start (7-deep HBM prefetch), outgoing
// rows re-loaded in-body (L2-hot). Horizontal 7-window: prefix-shuffle trick
// (4 DS ops/stat). No LDS, no barriers.
__global__ __launch_bounds__(256, 4) void ssim_stream_kernel(
    const float* __restrict__ X, const float* __restrict__ Y,
    const float* __restrict__ mmpart, float* __restrict__ part)
{
    const int lane  = threadIdx.x & 63;
    const int wid   = threadIdx.x >> 6;
    const int chunk = blockIdx.x;               // 0..2
    const int band  = blockIdx.y * WPB + wid;   // 0..39
    const int img   = blockIdx.z;               // 0..63
    if (band >= NBAND) return;                  // wave-uniform exit, no barriers

    // fold chunk min/max -> C1, C2 (uniform; hidden under prologue loads)
    float mn = 1e38f, mx = -1e38f;
    #pragma unroll
    for (int ch = 0; ch < CHUNKS; ++ch) {
        mn = fminf(mn, mmpart[2 * (img * CHUNKS + ch)]);
        mx = fmaxf(mx, mmpart[2 * (img * CHUNKS + ch) + 1]);
    }
    const float dr = mx - mn;
    const float C1 = (0.01f * dr) * (0.01f * dr);
    const float C2 = (0.03f * dr) * (0.03f * dr);
    const f32x2 C1v = {C1, C1};
    const f32x2 C2v = {C2, C2};
    const f32x2 inv2  = {1.0f / 49.0f, 1.0f / 49.0f};
    const f32x2 covn2 = {49.0f / 48.0f, 49.0f / 48.0f};

    // chunk geometry
    const int cbase  = (chunk == 0) ? 0 : (chunk == 1) ? 248 : 496;
    const int out_lo = (chunk == 0) ? 0 : (chunk == 1) ? 250 : 498;
    const int out_hi = (chunk == 0) ? 249 : (chunk == 1) ? 497 : 505;

    const int col0  = cbase + 4 * lane;             // logical first col
    const int col0c = (col0 < 508) ? col0 : 508;    // clamped, 16B aligned
    f32x2 vm01, vm23;
    {
        float v[4];
        #pragma unroll
        for (int j = 0; j < 4; ++j) {
            int oc = col0 + j;
            v[j] = (oc >= out_lo && oc <= out_hi) ? 1.0f : 0.0f;
        }
        vm01 = (f32x2){v[0], v[1]};
        vm23 = (f32x2){v[2], v[3]};
    }

    const int oy0 = band * BH;
    const int nvalid = (OH - oy0) < BH ? (OH - oy0) : BH;   // 14 or 2

    const float* px = X + (size_t)img * NPIX + col0c;
    const float* py = Y + (size_t)img * NPIX + col0c;

    // packed running vertical sums: [0]=cols 0,1  [1]=cols 2,3
    f32x2 Vx[2]  = {{0,0},{0,0}}, Vy[2]  = {{0,0},{0,0}};
    f32x2 Vxy[2] = {{0,0},{0,0}}, Vss[2] = {{0,0},{0,0}};

    #define VADD(xa, ya)                                                     \
    {                                                                        \
        f32x2 xl = (xa).lo, xh = (xa).hi, yl = (ya).lo, yh = (ya).hi;        \
        Vx[0] += xl; Vx[1] += xh; Vy[0] += yl; Vy[1] += yh;                  \
        Vxy[0] += xl * yl; Vxy[1] += xh * yh;                                \
        Vss[0] += xl * xl + yl * yl; Vss[1] += xh * xh + yh * yh;            \
    }
    #define VSUB(xa, ya)                                                     \
    {                                                                        \
        f32x2 xl = (xa).lo, xh = (xa).hi, yl = (ya).lo, yh = (ya).hi;        \
        Vx[0] -= xl; Vx[1] -= xh; Vy[0] -= yl; Vy[1] -= yh;                  \
        Vxy[0] -= xl * yl; Vxy[1] -= xh * yh;                                \
        Vss[0] -= xl * xl + yl * yl; Vss[1] -= xh * xh + yh * yh;            \
    }

    // prologue: accumulate rows oy0..oy0+5 (max 509, no clamp needed)
    #pragma unroll
    for (int k = 0; k < 6; ++k) {
        f32x4 xa = *(const f32x4*)(px + (size_t)(oy0 + k) * Wc);
        f32x4 ya = *(const f32x4*)(py + (size_t)(oy0 + k) * Wc);
        VADD(xa, ya)
    }

    f32x2 acc2 = {0.f, 0.f};

    // horizontal 7-window via prefix-shuffles: 4 DS ops per stat
    #define H7(V, W0, W1, W2, W3)                                            \
    {                                                                        \
        float v0 = V[0].x, v1 = V[0].y, v2 = V[1].x, v3 = V[1].y;            \
        float t01 = v0 + v1, u23 = v2 + v3;                                  \
        float P3 = t01 + v2, P4 = t01 + u23;                                 \
        float A3 = __shfl_down(P3, 1, 64);                                   \
        float A4 = __shfl_down(P4, 1, 64);                                   \
        float B1 = __shfl_down(v0, 2, 64);                                   \
        float B2 = __shfl_down(t01, 2, 64);                                  \
        float cc = u23 + A4;                                                 \
        W0 = P4 + A3;                                                        \
        W1 = cc + v1;                                                        \
        W2 = cc + B1;                                                        \
        W3 = (v3 + A4) + B2;                                                 \
    }

    #define SSIM2(wx, wy, wp, ws, vmv)                                       \
    {                                                                        \
        f32x2 ux   = wx * inv2;                                              \
        f32x2 uy   = wy * inv2;                                              \
        f32x2 uxuy = ux * uy;                                                \
        f32x2 u2   = ux * ux + uy * uy;                                      \
        f32x2 vxy  = (wp * inv2 - uxuy) * covn2;                             \
        f32x2 vss  = (ws * inv2 - u2) * covn2;                               \
        f32x2 A1   = uxuy + uxuy + C1v;                                      \
        f32x2 A2   = vxy + vxy + C2v;                                        \
        f32x2 B1   = u2 + C1v;                                               \
        f32x2 B2   = vss + C2v;                                              \
        f32x2 den  = B1 * B2;                                                \
        f32x2 num  = A1 * A2;                                                \
        f32x2 rv   = {__builtin_amdgcn_rcpf(den.x),                          \
                      __builtin_amdgcn_rcpf(den.y)};                         \
        acc2 += num * rv * vmv;                                              \
    }

    #pragma unroll
    for (int g = 0; g < 2; ++g) {
        // -------- batch prefetch: 7 incoming rows, both images (14 loads) --
        f32x4 lx[7], ly[7];
        #pragma unroll
        for (int k = 0; k < 7; ++k) {
            int r = oy0 + g * 7 + 6 + k;         // <= 523; clamp tail band
            if (r > 511) r = 511;
            lx[k] = *(const f32x4*)(px + (size_t)r * Wc);
            ly[k] = *(const f32x4*)(py + (size_t)r * Wc);
        }
        // -------- 7 compute iterations ------------------------------------
        #pragma unroll
        for (int k = 0; k < 7; ++k) {
            const int tt = g * 7 + k;
            VADD(lx[k], ly[k])
            const float rm = (tt < nvalid) ? 1.0f : 0.0f;
            const f32x2 vmr01 = vm01 * rm;
            const f32x2 vmr23 = vm23 * rm;
            float Wx0, Wx1, Wx2, Wx3;  H7(Vx,  Wx0, Wx1, Wx2, Wx3)
            float Wy0, Wy1, Wy2, Wy3;  H7(Vy,  Wy0, Wy1, Wy2, Wy3)
            float Wp0, Wp1, Wp2, Wp3;  H7(Vxy, Wp0, Wp1, Wp2, Wp3)
            float Ws0, Ws1, Ws2, Ws3;  H7(Vss, Ws0, Ws1, Ws2, Ws3)
            f32x2 wx01 = {Wx0, Wx1}, wx23 = {Wx2, Wx3};
            f32x2 wy01 = {Wy0, Wy1}, wy23 = {Wy2, Wy3};
            f32x2 wp01 = {Wp0, Wp1}, wp23 = {Wp2, Wp3};
            f32x2 ws01 = {Ws0, Ws1}, ws23 = {Ws2, Ws3};
            SSIM2(wx01, wy01, wp01, ws01, vmr01)
            SSIM2(wx23, wy23, wp23, ws23, vmr23)
            // outgoing row tt (read 6 iters ago -> L2-hot)
            int ro = oy0 + tt;                   // <= 517; clamp tail band
            if (ro > 511) ro = 511;
            f32x4 xo = *(const f32x4*)(px + (size_t)ro * Wc);
            f32x4 yo = *(const f32x4*)(py + (size_t)ro * Wc);
            VSUB(xo, yo)
        }
    }

    #undef SSIM2
    #undef H7
    #undef VADD
    #undef VSUB

    float acc = acc2.x + acc2.y;
    // deterministic wave reduce
    #pragma unroll
    for (int off = 1; off < 64; off <<= 1)
        acc += __shfl_xor(acc, off, 64);
    if (lane == 0)
        part[((size_t)img * NBAND + band) * NW + chunk] = acc;
}

// ---------------- Kernel 3: final deterministic f64 reduction ---------------
__global__ __launch_bounds__(1024) void final_reduce_kernel(
    const float* __restrict__ part, float* __restrict__ out)
{
    __shared__ double sd[1024];
    double s = 0.0;
    for (int i = threadIdx.x; i < NPART; i += 1024)
        s += (double)part[i];
    sd[threadIdx.x] = s;
    __syncthreads();
    for (int off = 512; off > 0; off >>= 1) {
        if (threadIdx.x < off) sd[threadIdx.x] += sd[threadIdx.x + off];
        __syncthreads();
    }
    if (threadIdx.x == 0)
        out[0] = (float)(sd[0] / ((double)BATCH * OH * OW));
}

extern "C" void kernel_launch(void* const* d_in, const int* in_sizes, int n_in,
                              void* d_out, int out_size, void* d_ws, size_t ws_size,
                              hipStream_t stream) {
    const float* X = (const float*)d_in[0];
    const float* Y = (const float*)d_in[1];
    float* out = (float*)d_out;
    float* ws  = (float*)d_ws;

    float* mmpart = ws;                 // 2 * BATCH * CHUNKS = 2048 floats
    float* part   = ws + 2048;          // NPART = 7104 floats

    mm_part_kernel<<<BATCH * CHUNKS, 256, 0, stream>>>(X, Y, mmpart);
    dim3 grid(NW, GYD, BATCH);
    ssim_stream_kernel<<<grid, 64 * WPB, 0, stream>>>(X, Y, mmpart, part);
    final_reduce_kernel<<<1, 1024, 0, stream>>>(part, out);
}